// Round 6
// baseline (627.985 us; speedup 1.0000x reference)
//
#include <hip/hip_runtime.h>

#define DIN 256
#define DH  128
#define DE  64

typedef __attribute__((ext_vector_type(8))) short short8;
typedef __attribute__((ext_vector_type(4))) float f32x4;
typedef __attribute__((ext_vector_type(4))) unsigned short us4;

__device__ inline unsigned short f2bf(float f) {
    unsigned u = __float_as_uint(f);
    return (unsigned short)((u + 0x7FFFu + ((u >> 16) & 1u)) >> 16);
}
__device__ inline float bf2f(unsigned short h) {
    return __uint_as_float((unsigned)h << 16);
}

__device__ inline void gload16(const void* g, void* l) {
    __builtin_amdgcn_global_load_lds(
        (const __attribute__((address_space(1))) void*)g,
        (__attribute__((address_space(3))) void*)l, 16, 0, 0);
}

// ---------------------------------------------------------------- CSR build

__global__ void init_counts_kernel(int* __restrict__ counts, int n) {
    int i = blockIdx.x * blockDim.x + threadIdx.x;
    if (i < n) counts[i] = 0;
}

__global__ void count_edges_kernel(const int* __restrict__ dst,
                                   int* __restrict__ counts, int E) {
    int e = blockIdx.x * blockDim.x + threadIdx.x;
    if (e < E) atomicAdd(&counts[dst[e]], 1);
}

__global__ void dinv_kernel(const int* __restrict__ counts,
                            float* __restrict__ dinv, int n) {
    int i = blockIdx.x * blockDim.x + threadIdx.x;
    if (i < n) dinv[i] = rsqrtf((float)counts[i] + 1.0f);
}

__global__ void scan1_kernel(const int* __restrict__ counts,
                             int* __restrict__ rowptr,
                             int* __restrict__ blocksums, int n) {
    __shared__ int sd[256];
    int t = threadIdx.x;
    int base = blockIdx.x * 1024 + t * 4;
    int v[4];
#pragma unroll
    for (int i = 0; i < 4; i++) v[i] = (base + i < n) ? counts[base + i] : 0;
    int tsum = v[0] + v[1] + v[2] + v[3];
    sd[t] = tsum;
    __syncthreads();
    for (int off = 1; off < 256; off <<= 1) {
        int x = (t >= off) ? sd[t - off] : 0;
        __syncthreads();
        sd[t] += x;
        __syncthreads();
    }
    int p = sd[t] - tsum;
#pragma unroll
    for (int i = 0; i < 4; i++) {
        if (base + i < n) rowptr[base + i] = p;
        p += v[i];
    }
    if (t == 255) blocksums[blockIdx.x] = sd[255];
}

__global__ void scan2_kernel(int* __restrict__ blocksums, int nb) {
    if (threadIdx.x == 0 && blockIdx.x == 0) {
        int run = 0;
        for (int i = 0; i < nb; i++) {
            int x = blocksums[i];
            blocksums[i] = run;
            run += x;
        }
    }
}

__global__ void scan3_kernel(int* __restrict__ rowptr, int* __restrict__ cursor,
                             const int* __restrict__ blocksums, int n, int E) {
    int i = blockIdx.x * blockDim.x + threadIdx.x;
    if (i < n) {
        int r = rowptr[i] + blocksums[i >> 10];
        rowptr[i] = r;
        cursor[i] = r;
    }
    if (i == 0) rowptr[n] = E;
}

__global__ void fill_csr_kernel(const int* __restrict__ src,
                                const int* __restrict__ dst,
                                int* __restrict__ cursor,
                                int* __restrict__ csr_src, int E) {
    int e = blockIdx.x * blockDim.x + threadIdx.x;
    if (e >= E) return;
    int s = src[e], d = dst[e];
    int pos = atomicAdd(&cursor[d], 1);
    csr_src[pos] = s;
}

// ------------------------------------------------- weight split + LDS-tile
// W[K][N] fp32 -> WtH/WtL bf16 arranged EXACTLY in the GEMM's B-LDS layout:
// tile (cb, chunk) holds 64 cols x 64 k; element (c_local, kk) at
// c_local*64 + ((kk/8) ^ (c_local&7))*8 + kk%8  (XOR-swizzle pre-applied so
// global_load_lds stages linearly and ds_read_b128 un-swizzles — rule 21).

__global__ void wtile_kernel(const float* __restrict__ W,
                             unsigned short* __restrict__ WtH,
                             unsigned short* __restrict__ WtL, int K, int N) {
    int i = blockIdx.x * blockDim.x + threadIdx.x;
    if (i >= K * N) return;
    int k = i / N, n = i % N;
    float v = W[i];
    unsigned short h = f2bf(v);
    unsigned short lo = f2bf(v - bf2f(h));
    int cb = n >> 6, cl = n & 63;
    int chunk = k >> 6, kk = k & 63;
    int s = kk >> 3, e = kk & 7;
    size_t idx = (size_t)(cb * (K >> 6) + chunk) * (64 * 64) + cl * 64 +
                 ((s ^ (cl & 7)) * 8) + e;
    WtH[idx] = h;
    WtL[idx] = lo;
}

// ------------------------------------------------------- MFMA bf16x3 GEMM
// C[M,N] = A * W (+bias)(+relu)(x dinv[row] prescale). BM=128, BK=64,
// 4 waves, wave = 32 rows x 64 cols. Both operands via global_load_lds;
// 48 KB LDS -> 3 blocks/CU (TLP is the latency-hiding at tiny K).
// mfma_f32_16x16x32_bf16: A row=l&15,k=8*(l>>4)+e; B col=l&15;
// D col=l&15,row=4*(l>>4)+e (verified rounds 3-5).

template <int K, bool AFP32, bool BIAS, bool RELU, bool SPLIT, bool PRESCALE>
__global__ __launch_bounds__(256, 3) void mfma_gemm(
    const void* __restrict__ Agh, const void* __restrict__ Agl,
    const unsigned short* __restrict__ WtH,
    const unsigned short* __restrict__ WtL, const float* __restrict__ bias,
    const float* __restrict__ dinv, float* __restrict__ C,
    unsigned short* __restrict__ Oh, unsigned short* __restrict__ Ol, int M,
    int NN) {
    constexpr int CF = 4;
    constexpr int CHUNKS = K / 64;
    __shared__ unsigned short Ath[128 * 64];
    __shared__ unsigned short Atl[128 * 64];
    __shared__ unsigned short Bth[64 * 64];
    __shared__ unsigned short Btl[64 * 64];

    int t = threadIdx.x;
    int wid = t >> 6;
    int l = t & 63;
    int lr = l & 15, lk = l >> 4;
    int row0 = blockIdx.x * 128;
    int col0 = blockIdx.y * 64;

    f32x4 acc0[CF], acc1[CF];
#pragma unroll
    for (int j = 0; j < CF; j++) {
        acc0[j] = (f32x4){0.f, 0.f, 0.f, 0.f};
        acc1[j] = (f32x4){0.f, 0.f, 0.f, 0.f};
    }

    for (int c = 0; c < CHUNKS; ++c) {
        int k0 = c * 64;
        // ---- stage B tile (pre-swizzled, contiguous)
        size_t bbase = (size_t)(blockIdx.y * CHUNKS + c) * (64 * 64);
#pragma unroll
        for (int i = 0; i < 2; i++) {
            int idx = (i * 256 + t) * 8;
            gload16(WtH + bbase + idx, &Bth[idx]);
            gload16(WtL + bbase + idx, &Btl[idx]);
        }
        // ---- stage A tile
        if (AFP32) {
            const float* A = (const float*)Agh;
#pragma unroll
            for (int i = 0; i < 4; i++) {
                int row = i * 32 + (t >> 3);
                int gr = row0 + row;
                if (gr >= M) gr = M - 1;
                int ss = (t & 7) ^ (row & 7);
                const float* sp = A + (size_t)gr * K + k0 + ss * 8;
                float4 f0 = *(const float4*)sp;
                float4 f1 = *(const float4*)(sp + 4);
                float fv[8] = {f0.x, f0.y, f0.z, f0.w,
                               f1.x, f1.y, f1.z, f1.w};
                short8 hv, lv;
#pragma unroll
                for (int e = 0; e < 8; e++) {
                    unsigned short h = f2bf(fv[e]);
                    hv[e] = (short)h;
                    lv[e] = (short)f2bf(fv[e] - bf2f(h));
                }
                int li = (i * 256 + t) * 8;  // == row*64 + (t&7)*8
                *(short8*)&Ath[li] = hv;
                *(short8*)&Atl[li] = lv;
            }
        } else {
            const unsigned short* Ah = (const unsigned short*)Agh;
            const unsigned short* Al = (const unsigned short*)Agl;
#pragma unroll
            for (int i = 0; i < 4; i++) {
                int row = i * 32 + (t >> 3);
                int gr = row0 + row;
                if (gr >= M) gr = M - 1;
                int ss = (t & 7) ^ (row & 7);
                size_t go = (size_t)gr * K + k0 + ss * 8;
                gload16(Ah + go, &Ath[(i * 256 + t) * 8]);
                gload16(Al + go, &Atl[(i * 256 + t) * 8]);
            }
        }
        __syncthreads();

#pragma unroll
        for (int ks = 0; ks < 2; ks++) {
            int r0 = wid * 32 + lr;
            int r1 = r0 + 16;
            int s = ks * 4 + lk;
            short8 a0h = *(const short8*)&Ath[r0 * 64 + (s ^ (r0 & 7)) * 8];
            short8 a0l = *(const short8*)&Atl[r0 * 64 + (s ^ (r0 & 7)) * 8];
            short8 a1h = *(const short8*)&Ath[r1 * 64 + (s ^ (r1 & 7)) * 8];
            short8 a1l = *(const short8*)&Atl[r1 * 64 + (s ^ (r1 & 7)) * 8];
#pragma unroll
            for (int j = 0; j < CF; j++) {
                int bo = (j * 16 + lr) * 64 + ((s ^ (lr & 7)) * 8);
                short8 bh = *(const short8*)&Bth[bo];
                short8 bl = *(const short8*)&Btl[bo];
                acc0[j] = __builtin_amdgcn_mfma_f32_16x16x32_bf16(
                    a0h, bh, acc0[j], 0, 0, 0);
                acc0[j] = __builtin_amdgcn_mfma_f32_16x16x32_bf16(
                    a0l, bh, acc0[j], 0, 0, 0);
                acc0[j] = __builtin_amdgcn_mfma_f32_16x16x32_bf16(
                    a0h, bl, acc0[j], 0, 0, 0);
                acc1[j] = __builtin_amdgcn_mfma_f32_16x16x32_bf16(
                    a1h, bh, acc1[j], 0, 0, 0);
                acc1[j] = __builtin_amdgcn_mfma_f32_16x16x32_bf16(
                    a1l, bh, acc1[j], 0, 0, 0);
                acc1[j] = __builtin_amdgcn_mfma_f32_16x16x32_bf16(
                    a1h, bl, acc1[j], 0, 0, 0);
            }
        }
        __syncthreads();
    }

#pragma unroll
    for (int j = 0; j < CF; j++) {
        int col = col0 + j * 16 + lr;
        float bb = BIAS ? bias[col] : 0.f;
#pragma unroll
        for (int e = 0; e < 4; e++) {
            int r = row0 + wid * 32 + lk * 4 + e;
#pragma unroll
            for (int rf = 0; rf < 2; rf++) {
                int rr = r + rf * 16;
                if (rr >= M) continue;
                float v = (rf ? acc1[j][e] : acc0[j][e]) + bb;
                if (PRESCALE) v *= dinv[rr];
                if (RELU) v = fmaxf(v, 0.f);
                if (SPLIT) {
                    unsigned short h = f2bf(v);
                    Oh[(size_t)rr * NN + col] = h;
                    Ol[(size_t)rr * NN + col] = f2bf(v - bf2f(h));
                } else {
                    C[(size_t)rr * NN + col] = v;
                }
            }
        }
    }
}

// ------------------------------------------------------------- aggregation
// GEMM wrote g = u * dinv[row]. Then
// out[v] = (relu)( dinv[v] * (sum_{e: dst==v} g[src_e] + g[v]) + bias ).
// TPN = D/16 lanes/node, 4 float4 chunks/lane, 4-edge unroll -> 16 gathers
// in flight per lane. No per-edge coef load.

template <int D, bool RELU, bool WF32>
__global__ __launch_bounds__(256) void agg_kernel(
    const float* __restrict__ g, const float* __restrict__ dinv,
    const int* __restrict__ rowptr, const int* __restrict__ csr_src,
    const float* __restrict__ bias, unsigned short* __restrict__ outh,
    unsigned short* __restrict__ outl, float* __restrict__ outf, int n) {
    constexpr int TPN = D / 16;
    constexpr int NPB = 256 / TPN;
    int v = blockIdx.x * NPB + threadIdx.x / TPN;
    int d = threadIdx.x % TPN;
    if (v >= n) return;

    const float* gv = g + (size_t)v * D + d * 4;
    float4 accA[4], accB[4];
#pragma unroll
    for (int i = 0; i < 4; i++) {
        accA[i] = *(const float4*)(gv + i * TPN * 4);
        accB[i] = make_float4(0.f, 0.f, 0.f, 0.f);
    }

    int e0 = rowptr[v], e1 = rowptr[v + 1];
    int e = e0;
    for (; e + 4 <= e1; e += 4) {
        int s0 = csr_src[e], s1 = csr_src[e + 1];
        int s2 = csr_src[e + 2], s3 = csr_src[e + 3];
        const float* p0 = g + (size_t)s0 * D + d * 4;
        const float* p1 = g + (size_t)s1 * D + d * 4;
        const float* p2 = g + (size_t)s2 * D + d * 4;
        const float* p3 = g + (size_t)s3 * D + d * 4;
        float4 g0[4], g1[4], g2[4], g3[4];
#pragma unroll
        for (int i = 0; i < 4; i++) g0[i] = *(const float4*)(p0 + i * TPN * 4);
#pragma unroll
        for (int i = 0; i < 4; i++) g1[i] = *(const float4*)(p1 + i * TPN * 4);
#pragma unroll
        for (int i = 0; i < 4; i++) g2[i] = *(const float4*)(p2 + i * TPN * 4);
#pragma unroll
        for (int i = 0; i < 4; i++) g3[i] = *(const float4*)(p3 + i * TPN * 4);
#pragma unroll
        for (int i = 0; i < 4; i++) {
            accA[i].x += g0[i].x + g2[i].x;
            accA[i].y += g0[i].y + g2[i].y;
            accA[i].z += g0[i].z + g2[i].z;
            accA[i].w += g0[i].w + g2[i].w;
            accB[i].x += g1[i].x + g3[i].x;
            accB[i].y += g1[i].y + g3[i].y;
            accB[i].z += g1[i].z + g3[i].z;
            accB[i].w += g1[i].w + g3[i].w;
        }
    }
    for (; e + 2 <= e1; e += 2) {
        int s0 = csr_src[e], s1 = csr_src[e + 1];
        const float* p0 = g + (size_t)s0 * D + d * 4;
        const float* p1 = g + (size_t)s1 * D + d * 4;
        float4 g0[4], g1[4];
#pragma unroll
        for (int i = 0; i < 4; i++) g0[i] = *(const float4*)(p0 + i * TPN * 4);
#pragma unroll
        for (int i = 0; i < 4; i++) g1[i] = *(const float4*)(p1 + i * TPN * 4);
#pragma unroll
        for (int i = 0; i < 4; i++) {
            accA[i].x += g0[i].x;
            accA[i].y += g0[i].y;
            accA[i].z += g0[i].z;
            accA[i].w += g0[i].w;
            accB[i].x += g1[i].x;
            accB[i].y += g1[i].y;
            accB[i].z += g1[i].z;
            accB[i].w += g1[i].w;
        }
    }
    if (e < e1) {
        int s0 = csr_src[e];
        const float* p0 = g + (size_t)s0 * D + d * 4;
#pragma unroll
        for (int i = 0; i < 4; i++) {
            float4 gg = *(const float4*)(p0 + i * TPN * 4);
            accA[i].x += gg.x;
            accA[i].y += gg.y;
            accA[i].z += gg.z;
            accA[i].w += gg.w;
        }
    }

    float dv = dinv[v];
#pragma unroll
    for (int i = 0; i < 4; i++) {
        float4 bv = *(const float4*)&bias[(i * TPN + d) * 4];
        float4 r;
        r.x = fmaf(dv, accA[i].x + accB[i].x, bv.x);
        r.y = fmaf(dv, accA[i].y + accB[i].y, bv.y);
        r.z = fmaf(dv, accA[i].z + accB[i].z, bv.z);
        r.w = fmaf(dv, accA[i].w + accB[i].w, bv.w);
        if (RELU) {
            r.x = fmaxf(r.x, 0.f);
            r.y = fmaxf(r.y, 0.f);
            r.z = fmaxf(r.z, 0.f);
            r.w = fmaxf(r.w, 0.f);
        }
        size_t o = (size_t)v * D + (i * TPN + d) * 4;
        float av[4] = {r.x, r.y, r.z, r.w};
        us4 hw, lw;
#pragma unroll
        for (int q = 0; q < 4; q++) {
            unsigned short hh = f2bf(av[q]);
            hw[q] = hh;
            lw[q] = f2bf(av[q] - bf2f(hh));
        }
        *(us4*)&outh[o] = hw;
        *(us4*)&outl[o] = lw;
        if (WF32) *(float4*)&outf[o] = r;
    }
}

// ---------------------------------------------------------------- launcher

extern "C" void kernel_launch(void* const* d_in, const int* in_sizes, int n_in,
                              void* d_out, int out_size, void* d_ws,
                              size_t ws_size, hipStream_t stream) {
    const float* x   = (const float*)d_in[0];
    const int*   ei  = (const int*)d_in[1];
    const float* W1  = (const float*)d_in[2];
    const float* b1  = (const float*)d_in[3];
    const float* W2  = (const float*)d_in[4];
    const float* b2  = (const float*)d_in[5];
    const float* W3  = (const float*)d_in[6];
    const float* b3  = (const float*)d_in[7];
    const float* Wd1 = (const float*)d_in[8];
    const float* bd1 = (const float*)d_in[9];
    const float* Wd2 = (const float*)d_in[10];
    const float* bd2 = (const float*)d_in[11];

    const int N = in_sizes[0] / DIN;
    const int E = in_sizes[1] / 2;
    const int* src = ei;
    const int* dst = ei + E;

    char* w = (char*)d_ws;
    auto alloc = [&](size_t bytes) -> char* {
        char* p = w;
        w += (bytes + 255) & ~(size_t)255;
        return p;
    };
    int*   counts    = (int*)alloc((size_t)N * 4);
    float* dinv      = (float*)alloc((size_t)N * 4);
    int*   rowptr    = (int*)alloc((size_t)(N + 1) * 4);
    int*   cursor    = (int*)alloc((size_t)N * 4);
    int*   blocksums = (int*)alloc(4096);
    int*   csr_src   = (int*)alloc((size_t)E * 4);
    unsigned short* hh = (unsigned short*)alloc((size_t)N * DH * 2);
    unsigned short* hl = (unsigned short*)alloc((size_t)N * DH * 2);
    unsigned short* W1h  = (unsigned short*)alloc(DIN * DH * 2);
    unsigned short* W1l  = (unsigned short*)alloc(DIN * DH * 2);
    unsigned short* W2h  = (unsigned short*)alloc(DH * DH * 2);
    unsigned short* W2l  = (unsigned short*)alloc(DH * DH * 2);
    unsigned short* W3h  = (unsigned short*)alloc(DH * DE * 2);
    unsigned short* W3l  = (unsigned short*)alloc(DH * DE * 2);
    unsigned short* Wd1h = (unsigned short*)alloc(DE * DH * 2);
    unsigned short* Wd1l = (unsigned short*)alloc(DE * DH * 2);
    unsigned short* Wd2h = (unsigned short*)alloc(DH * DIN * 2);
    unsigned short* Wd2l = (unsigned short*)alloc(DH * DIN * 2);

    float* zout = (float*)d_out;               // [N, 64]
    float* xhat = zout + (size_t)N * DE;       // [N, 256]
    float* S1   = xhat;                        // [N,128] scratch in xhat
    unsigned short* zh = (unsigned short*)(xhat + (size_t)N * DH);
    unsigned short* zl = zh + (size_t)N * DE;
    unsigned short* rh = hh;
    unsigned short* rl = hl;

    dim3 blk(256);
    int gN = (N + 255) / 256, gE = (E + 255) / 256;

    init_counts_kernel<<<gN, blk, 0, stream>>>(counts, N);
    count_edges_kernel<<<gE, blk, 0, stream>>>(dst, counts, E);
    dinv_kernel<<<gN, blk, 0, stream>>>(counts, dinv, N);
    int nb = (N + 1023) / 1024;
    scan1_kernel<<<nb, blk, 0, stream>>>(counts, rowptr, blocksums, N);
    scan2_kernel<<<1, 64, 0, stream>>>(blocksums, nb);
    scan3_kernel<<<gN, blk, 0, stream>>>(rowptr, cursor, blocksums, N, E);
    fill_csr_kernel<<<gE, blk, 0, stream>>>(src, dst, cursor, csr_src, E);

    // weight split into pre-swizzled 64-col B-LDS tile layout
    wtile_kernel<<<(DIN * DH + 255) / 256, blk, 0, stream>>>(W1, W1h, W1l,
                                                             DIN, DH);
    wtile_kernel<<<(DH * DH + 255) / 256, blk, 0, stream>>>(W2, W2h, W2l,
                                                            DH, DH);
    wtile_kernel<<<(DH * DE + 255) / 256, blk, 0, stream>>>(W3, W3h, W3l,
                                                            DH, DE);
    wtile_kernel<<<(DE * DH + 255) / 256, blk, 0, stream>>>(Wd1, Wd1h, Wd1l,
                                                            DE, DH);
    wtile_kernel<<<(DH * DIN + 255) / 256, blk, 0, stream>>>(Wd2, Wd2h, Wd2l,
                                                             DH, DIN);

    int gm = (N + 127) / 128;

    // g1 = (x @ W1) * dinv ; h1 = relu(dinv*(sum g1) + b1)
    mfma_gemm<DIN, true, false, false, false, true><<<dim3(gm, 2), blk, 0,
        stream>>>(x, nullptr, W1h, W1l, nullptr, dinv, S1, nullptr, nullptr,
                  N, DH);
    agg_kernel<DH, true, false><<<(N + 31) / 32, blk, 0, stream>>>(
        S1, dinv, rowptr, csr_src, b1, hh, hl, nullptr, N);
    // g2 = (h1 @ W2) * dinv ; h2 = relu(dinv*(sum g2) + b2)
    mfma_gemm<DH, false, false, false, false, true><<<dim3(gm, 2), blk, 0,
        stream>>>(hh, hl, W2h, W2l, nullptr, dinv, S1, nullptr, nullptr,
                  N, DH);
    agg_kernel<DH, true, false><<<(N + 31) / 32, blk, 0, stream>>>(
        S1, dinv, rowptr, csr_src, b2, hh, hl, nullptr, N);
    // g3 = (h2 @ W3) * dinv ; z = dinv*(sum g3) + b3
    mfma_gemm<DH, false, false, false, false, true><<<dim3(gm, 1), blk, 0,
        stream>>>(hh, hl, W3h, W3l, nullptr, dinv, S1, nullptr, nullptr,
                  N, DE);
    agg_kernel<DE, false, true><<<(N + 63) / 64, blk, 0, stream>>>(
        S1, dinv, rowptr, csr_src, b3, zh, zl, zout, N);
    // r = relu(z @ Wd1 + bd1)  -> bf16 hi/lo directly
    mfma_gemm<DE, false, true, true, true, false><<<dim3(gm, 2), blk, 0,
        stream>>>(zh, zl, Wd1h, Wd1l, bd1, nullptr, nullptr, rh, rl, N, DH);
    // x_hat = r @ Wd2 + bd2
    mfma_gemm<DH, false, true, false, false, false><<<dim3(gm, 4), blk, 0,
        stream>>>(rh, rl, Wd2h, Wd2l, bd2, nullptr, xhat, nullptr, nullptr,
                  N, DIN);
}